// Round 6
// baseline (1335.718 us; speedup 1.0000x reference)
//
#include <hip/hip_runtime.h>

#define N_NODES 50000
#define N_EDGES 800000
#define F 128
#define BN_EPS 1e-5f
#define SLOPE 0.22916666666666666f  // RReLU eval slope 11/48

#define NBKT 196          // coarse buckets (tgt>>8)
#define P1_CHUNK 4096
#define P1_EPB 16
#define P1_BLKS 196       // ceil(N_EDGES/P1_CHUNK)
#define CASTX_BLKS 6250   // N_NODES*F/4/256 (exact)
#define CASTW_BLKS 64
#define BKT_FINAL_CAP 9984   // cnt_max + pad slack; 39.9 KB LDS
#define BKT_STRIDE 10240     // fixed final-recs stride per bucket (no cross-bucket scan)
#define MYR_CAP 18           // ceil(max bucket cnt / 256); Poisson(4082) max ~4400
#define N_RT 3125         // N_NODES/16 row-tiles (exact)
#define NPART 8           // BN-stat partial arrays (atomic contention relief)

typedef __attribute__((ext_vector_type(8))) short bf16x8;
typedef __attribute__((ext_vector_type(4))) float f32x4;
typedef unsigned long long u64;

__device__ __forceinline__ float bf2f(ushort u) {
    union { uint i; float f; } v; v.i = (uint)u << 16; return v.f;
}
__device__ __forceinline__ ushort f2bf(float f) {
    union { float f; uint i; } v; v.f = f;
    uint r = v.i + 0x7fffu + ((v.i >> 16) & 1u);  // RNE
    return (ushort)(r >> 16);
}
// pack 2 f32 -> 2 bf16 (lo -> [15:0], hi -> [31:16]) in one instr
__device__ __forceinline__ uint cvtpk(float lo, float hi) {
    uint r;
    asm("v_cvt_pk_bf16_f32 %0, %1, %2" : "=v"(r) : "v"(lo), "v"(hi));
    return r;
}

// ============ s1p: pass 1 (block-local bucket grouping, NO global atomics)
//              + x/W bf16 casts, one launch ============
// staging record: bits[0:31] = src | bf16(w)<<16 ; bits[32:63] = tgt
__global__ __launch_bounds__(256) void s1p_k(const int* __restrict__ src,
        const int* __restrict__ tgt, const float* __restrict__ ew,
        u64* __restrict__ stg, int* __restrict__ cntM, int* __restrict__ offM,
        const float* __restrict__ x, ushort* __restrict__ xb,
        const float* __restrict__ W1r, const float* __restrict__ W1t,
        const float* __restrict__ W2r, const float* __restrict__ W2t,
        ushort* __restrict__ wb) {
    const int b = blockIdx.x;
    if (b >= P1_BLKS) {
        if (b < P1_BLKS + CASTX_BLKS) {
            int i = (b - P1_BLKS) * 256 + threadIdx.x;
            float4 v = reinterpret_cast<const float4*>(x)[i];
            ushort4 o;
            o.x = f2bf(v.x); o.y = f2bf(v.y); o.z = f2bf(v.z); o.w = f2bf(v.w);
            reinterpret_cast<ushort4*>(xb)[i] = o;
        } else {
            int i = (b - P1_BLKS - CASTX_BLKS) * 256 + threadIdx.x;  // 16384 total
            int m = i >> 12;
            int j = i & 4095;
            const float* sp = (m == 0) ? W1r : (m == 1) ? W1t : (m == 2) ? W2r : W2t;
            float4 v = reinterpret_cast<const float4*>(sp)[j];
            ushort4 o;
            o.x = f2bf(v.x); o.y = f2bf(v.y); o.z = f2bf(v.z); o.w = f2bf(v.w);
            reinterpret_cast<ushort4*>(wb)[i] = o;
        }
        return;
    }
    // ---- sort pass 1 (block-local only) ----
    __shared__ uint cnt[256];
    __shared__ uint base[256];
    __shared__ uint lcur[256];
    __shared__ u64 lrec[P1_CHUNK];  // 32 KB

    const int e0 = b * P1_CHUNK;
    const int nE = min(P1_CHUNK, N_EDGES - e0);
    cnt[threadIdx.x] = 0;
    __syncthreads();

    u64 myrec[P1_EPB];
    bool myok[P1_EPB];
#pragma unroll
    for (int k = 0; k < P1_EPB; ++k) {
        int idx = threadIdx.x + (k << 8);
        bool ok = idx < nE;
        myok[k] = ok;
        if (ok) {
            int e = e0 + idx;
            uint t = (uint)tgt[e];
            uint lo = (uint)(ushort)src[e] | ((uint)f2bf(ew[e]) << 16);
            myrec[k] = (u64)lo | ((u64)t << 32);
            atomicAdd(&cnt[t >> 8], 1u);
        }
    }
    __syncthreads();
    uint v = cnt[threadIdx.x];
    base[threadIdx.x] = v;
    __syncthreads();
    for (int o = 1; o < 256; o <<= 1) {
        uint t = (threadIdx.x >= (unsigned)o) ? base[threadIdx.x - o] : 0;
        __syncthreads();
        base[threadIdx.x] += t;
        __syncthreads();
    }
    uint excl = base[threadIdx.x] - v;
    lcur[threadIdx.x] = excl;
    if (threadIdx.x < NBKT) {
        cntM[threadIdx.x * NBKT + b] = (int)v;
        offM[threadIdx.x * NBKT + b] = (int)excl;
    }
    __syncthreads();
#pragma unroll
    for (int k = 0; k < P1_EPB; ++k) {
        if (myok[k]) {
            uint bb = (uint)(myrec[k] >> 40);
            uint slot = atomicAdd(&lcur[bb], 1u);
            lrec[slot] = myrec[k];
        }
    }
    __syncthreads();
    for (int s = threadIdx.x; s < nE; s += 256)
        stg[(size_t)b * P1_CHUNK + s] = lrec[s];
}

// ============ sort pass 2: per bucket, fully independent (fixed output stride) ====
__global__ __launch_bounds__(256) void sort2_k(const int* __restrict__ cntM,
        const int* __restrict__ offM, const u64* __restrict__ stg,
        uint* __restrict__ recs, int2* __restrict__ rng,
        float* __restrict__ Sp, float* __restrict__ S2p) {
    __shared__ int soff[256];
    __shared__ int astart[256];
    __shared__ int lcnt[256];
    __shared__ int lcur[256];
    __shared__ int sc[256];
    __shared__ int tot_s;
    __shared__ uint lrec[BKT_FINAL_CAP];  // 39.9 KB
    const int B = blockIdx.x;
    const int tid = threadIdx.x;

    if (B < NPART && tid < 128) {         // zero BN partials (ready before fused<1>)
        Sp[B * 128 + tid] = 0.f;
        S2p[B * 128 + tid] = 0.f;
    }

    int c = (tid < NBKT) ? cntM[B * NBKT + tid] : 0;
    soff[tid] = (tid < NBKT) ? offM[B * NBKT + tid] : 0;
    sc[tid] = c;
    lcnt[tid] = 0;
    __syncthreads();
    for (int o = 1; o < 256; o <<= 1) {
        int t = (tid >= o) ? sc[tid - o] : 0;
        __syncthreads();
        sc[tid] += t;
        __syncthreads();
    }
    astart[tid] = sc[tid] - c;
    if (tid == 255) tot_s = sc[255];
    __syncthreads();
    const int tot = tot_s;

    u64 myr[MYR_CAP];
#pragma unroll
    for (int k = 0; k < MYR_CAP; ++k) {
        int i = tid + (k << 8);
        if (i < tot) {
            int lo = 0, hi = NBKT - 1;
            while (lo < hi) {
                int mid = (lo + hi + 1) >> 1;
                if (astart[mid] <= i) lo = mid; else hi = mid - 1;
            }
            int j = i - astart[lo];
            u64 r = stg[(size_t)lo * P1_CHUNK + soff[lo] + j];
            myr[k] = r;
            atomicAdd(&lcnt[(int)(r >> 32) & 255], 1);
        }
    }
    __syncthreads();
    const int node = B * 256 + tid;
    int myc = lcnt[tid];
    int myp = (myc + 3) & ~3;            // pad to x4 (zero filler = exact no-op)
    if (node >= N_NODES) myp = 0;
    sc[tid] = myp;
    __syncthreads();
    for (int o = 1; o < 256; o <<= 1) {
        int t = (tid >= o) ? sc[tid - o] : 0;
        __syncthreads();
        sc[tid] += t;
        __syncthreads();
    }
    const int myoff = sc[tid] - myp;
    const int ptot = sc[255];
    lcur[tid] = myoff;
    const int fbase = B * BKT_STRIDE;
    if (node < N_NODES) rng[node] = make_int2(fbase + myoff, fbase + myoff + myp);
    for (int i = tid; i < ptot; i += 256) lrec[i] = 0;
    __syncthreads();
#pragma unroll
    for (int k = 0; k < MYR_CAP; ++k) {
        int i = tid + (k << 8);
        if (i < tot) {
            u64 r = myr[k];
            int n = (int)(r >> 32) & 255;
            int p = atomicAdd(&lcur[n], 1);
            lrec[p] = (uint)r;
        }
    }
    __syncthreads();
    for (int i = tid; i < ptot; i += 256) recs[fbase + i] = lrec[i];
}

// ============ fused gather + dual-GEMM (one block = one 16-row tile) ============
// NEW gather: LDS f32 accumulation via ds_add_f32. The tile's record stream
// (contiguous, node-padded x4) is split into 16 flat chunks, one per (wave,quad).
// Each quad streams records: quad-uniform rec load + 16 lanes x 16B row slice +
// 8 atomic f32 adds. Row tracked by walking pointer over 17 node boundaries.
// Zero loop-carried register dependence -> loads pipeline freely.
template <int LAYER>
__global__ __launch_bounds__(256) void fused_k(
        const ushort* __restrict__ featb, const int2* __restrict__ rng,
        const uint* __restrict__ recs, const ushort* __restrict__ Wr,
        const ushort* __restrict__ Wt, const float* __restrict__ bias,
        const float* __restrict__ gamma, const float* __restrict__ beta,
        float* __restrict__ Sp, float* __restrict__ S2p,
        ushort* __restrict__ outh, float* __restrict__ outf) {
    __shared__ __align__(16) float accf[16][132];  // 8448 B, row pad 132 (bank spread)
    __shared__ __align__(16) uint aggu[16 * 64];   // 4 KB bf16 tile, XOR-swizzled
    __shared__ uint s16[20];                       // 17 node boundaries (abs positions)
    __shared__ __align__(16) float scs[128];
    __shared__ __align__(16) float shs[128];

    const int tid = threadIdx.x;
    const int lane = tid & 63;
    const int wave = tid >> 6;
    const int row0 = blockIdx.x * 16;
    const int quad = lane >> 4;
    const int l16 = lane & 15;

    // zero acc tile
    for (int k = tid; k < 16 * 132; k += 256) (&accf[0][0])[k] = 0.f;
    if (tid < 16) s16[tid] = (uint)rng[row0 + tid].x;
    if (tid == 16) s16[16] = (uint)rng[row0 + 15].y;
    if (LAYER == 2) {
        if (tid < 128) {
            float s = 0.f, q = 0.f;
#pragma unroll
            for (int p = 0; p < NPART; ++p) {
                s += Sp[p * 128 + tid];
                q += S2p[p * 128 + tid];
            }
            float mean = s * (1.f / N_NODES);
            float var = q * (1.f / N_NODES) - mean * mean;
            float inv = rsqrtf(var + BN_EPS);
            float sc = gamma[tid] * inv;
            scs[tid] = sc;
            shs[tid] = beta[tid] - mean * sc;
        }
    }
    __syncthreads();

    // per-lane BN constants for this lane's 8 features (layer 2 only)
    float lsc0 = 0.f, lsc1 = 0.f, lsc2 = 0.f, lsc3 = 0.f;
    float lsc4 = 0.f, lsc5 = 0.f, lsc6 = 0.f, lsc7 = 0.f;
    float lsh0 = 0.f, lsh1 = 0.f, lsh2 = 0.f, lsh3 = 0.f;
    float lsh4 = 0.f, lsh5 = 0.f, lsh6 = 0.f, lsh7 = 0.f;
    if (LAYER == 2) {
        const int fb0 = l16 * 8;
        lsc0 = scs[fb0 + 0]; lsc1 = scs[fb0 + 1]; lsc2 = scs[fb0 + 2]; lsc3 = scs[fb0 + 3];
        lsc4 = scs[fb0 + 4]; lsc5 = scs[fb0 + 5]; lsc6 = scs[fb0 + 6]; lsc7 = scs[fb0 + 7];
        lsh0 = shs[fb0 + 0]; lsh1 = shs[fb0 + 1]; lsh2 = shs[fb0 + 2]; lsh3 = shs[fb0 + 3];
        lsh4 = shs[fb0 + 4]; lsh5 = shs[fb0 + 5]; lsh6 = shs[fb0 + 6]; lsh7 = shs[fb0 + 7];
    }

    // ---- phase 1: streamed gather with LDS f32 accumulation ----
    {
        const uint t0 = s16[0], t1 = s16[16];
        const uint ptile = t1 - t0;
        const uint C = (ptile + 15) >> 4;      // chunk per (wave,quad)
        const uint qid = (uint)(wave * 4 + quad);
        uint p = t0 + qid * C;
        uint pe = min(p + C, t1);
        int row = 0;
        uint end = s16[1];
        const char* fb = (const char*)featb;
        const uint fbyte = (uint)l16 << 4;

        auto act = [&](float t) {
            if (LAYER == 2) { /* placeholder, specialized below */ }
            return t;
        };
        (void)act;

        for (; p < pe; ++p) {
            while (p >= end) { ++row; end = s16[row + 1]; }
            uint rec = recs[p];
            uint4 u = *reinterpret_cast<const uint4*>(fb + (((rec & 0xffffu) << 8) + fbyte));
            float w = __uint_as_float(rec & 0xffff0000u);   // bf16 weight in high bits
            float* arow = &accf[0][0] + row * 132 + l16 * 8;
            float ta, tb;
            ta = __uint_as_float(u.x << 16);
            tb = __uint_as_float(u.x & 0xffff0000u);
            if (LAYER == 2) {
                ta = fmaf(ta, lsc0, lsh0); ta = fmaxf(ta, ta * SLOPE);
                tb = fmaf(tb, lsc1, lsh1); tb = fmaxf(tb, tb * SLOPE);
            }
            unsafeAtomicAdd(&arow[0], w * ta);
            unsafeAtomicAdd(&arow[1], w * tb);
            ta = __uint_as_float(u.y << 16);
            tb = __uint_as_float(u.y & 0xffff0000u);
            if (LAYER == 2) {
                ta = fmaf(ta, lsc2, lsh2); ta = fmaxf(ta, ta * SLOPE);
                tb = fmaf(tb, lsc3, lsh3); tb = fmaxf(tb, tb * SLOPE);
            }
            unsafeAtomicAdd(&arow[2], w * ta);
            unsafeAtomicAdd(&arow[3], w * tb);
            ta = __uint_as_float(u.z << 16);
            tb = __uint_as_float(u.z & 0xffff0000u);
            if (LAYER == 2) {
                ta = fmaf(ta, lsc4, lsh4); ta = fmaxf(ta, ta * SLOPE);
                tb = fmaf(tb, lsc5, lsh5); tb = fmaxf(tb, tb * SLOPE);
            }
            unsafeAtomicAdd(&arow[4], w * ta);
            unsafeAtomicAdd(&arow[5], w * tb);
            ta = __uint_as_float(u.w << 16);
            tb = __uint_as_float(u.w & 0xffff0000u);
            if (LAYER == 2) {
                ta = fmaf(ta, lsc6, lsh6); ta = fmaxf(ta, ta * SLOPE);
                tb = fmaf(tb, lsc7, lsh7); tb = fmaxf(tb, tb * SLOPE);
            }
            unsafeAtomicAdd(&arow[6], w * ta);
            unsafeAtomicAdd(&arow[7], w * tb);
        }
    }
    __syncthreads();

    // ---- convert accf (f32) -> aggu (bf16, XOR-swizzled) ----
    {
        const int r = tid >> 4, c = tid & 15;
        const float* a = &accf[r][c * 8];
        uint4 o = make_uint4(cvtpk(a[0], a[1]), cvtpk(a[2], a[3]),
                             cvtpk(a[4], a[5]), cvtpk(a[6], a[7]));
        *reinterpret_cast<uint4*>(&aggu[(r * 64 + c * 4) ^ ((r & 7) << 2)]) = o;
    }
    __syncthreads();

    // ---- phase 2: dual GEMM, A(R) from LDS, A(T) from global, W from global ----
    const int cb = wave * 32;
    const float bias0 = bias[cb + l16];
    const float bias1 = bias[cb + 16 + l16];

    f32x4 acc0 = {0.f, 0.f, 0.f, 0.f};
    f32x4 acc1 = {0.f, 0.f, 0.f, 0.f};

#pragma unroll
    for (int s = 0; s < 4; ++s) {
        const int k0 = s * 32 + quad * 8;
        const int ai = (l16 * 64 + (k0 >> 1)) ^ ((l16 & 7) << 2);
        bf16x8 aR = *reinterpret_cast<const bf16x8*>(&aggu[ai]);
        bf16x8 w0 = *reinterpret_cast<const bf16x8*>(Wr + (cb + l16) * F + k0);
        bf16x8 w1 = *reinterpret_cast<const bf16x8*>(Wr + (cb + 16 + l16) * F + k0);
        acc0 = __builtin_amdgcn_mfma_f32_16x16x32_bf16(aR, w0, acc0, 0, 0, 0);
        acc1 = __builtin_amdgcn_mfma_f32_16x16x32_bf16(aR, w1, acc1, 0, 0, 0);
    }
#pragma unroll
    for (int s = 0; s < 4; ++s) {
        const int k0 = s * 32 + quad * 8;
        bf16x8 aT = *reinterpret_cast<const bf16x8*>(featb + (size_t)(row0 + l16) * F + k0);
        if (LAYER == 2) {
#pragma unroll
            for (int e = 0; e < 8; ++e) {
                float t = bf2f((ushort)aT[e]) * scs[k0 + e] + shs[k0 + e];
                t = fmaxf(t, t * SLOPE);
                aT[e] = (short)f2bf(t);
            }
        }
        bf16x8 w0 = *reinterpret_cast<const bf16x8*>(Wt + (cb + l16) * F + k0);
        bf16x8 w1 = *reinterpret_cast<const bf16x8*>(Wt + (cb + 16 + l16) * F + k0);
        acc0 = __builtin_amdgcn_mfma_f32_16x16x32_bf16(aT, w0, acc0, 0, 0, 0);
        acc1 = __builtin_amdgcn_mfma_f32_16x16x32_bf16(aT, w1, acc1, 0, 0, 0);
    }

    // ---- epilogue: C layout col=lane&15, row=quad*4+reg ----
    const int rbase = row0 + quad * 4;
    if (LAYER == 1) {
        float s0 = 0.f, q0 = 0.f, s1 = 0.f, q1 = 0.f;
#pragma unroll
        for (int g = 0; g < 4; ++g) {
            float v0 = acc0[g] + bias0;
            float v1 = acc1[g] + bias1;
            outh[(size_t)(rbase + g) * F + cb + l16] = f2bf(v0);
            outh[(size_t)(rbase + g) * F + cb + 16 + l16] = f2bf(v1);
            s0 += v0; q0 += v0 * v0;
            s1 += v1; q1 += v1 * v1;
        }
        s0 += __shfl_down(s0, 32); s0 += __shfl_down(s0, 16);
        q0 += __shfl_down(q0, 32); q0 += __shfl_down(q0, 16);
        s1 += __shfl_down(s1, 32); s1 += __shfl_down(s1, 16);
        q1 += __shfl_down(q1, 32); q1 += __shfl_down(q1, 16);
        if (lane < 16) {
            float* Sb = Sp + (size_t)(blockIdx.x & (NPART - 1)) * 128;
            float* S2b = S2p + (size_t)(blockIdx.x & (NPART - 1)) * 128;
            unsafeAtomicAdd(&Sb[cb + lane], s0);
            unsafeAtomicAdd(&S2b[cb + lane], q0);
            unsafeAtomicAdd(&Sb[cb + 16 + lane], s1);
            unsafeAtomicAdd(&S2b[cb + 16 + lane], q1);
        }
    } else {
#pragma unroll
        for (int g = 0; g < 4; ++g) {
            outf[(size_t)(rbase + g) * F + cb + l16] = acc0[g] + bias0;
            outf[(size_t)(rbase + g) * F + cb + 16 + l16] = acc1[g] + bias1;
        }
    }
}

extern "C" void kernel_launch(void* const* d_in, const int* in_sizes, int n_in,
                              void* d_out, int out_size, void* d_ws, size_t ws_size,
                              hipStream_t stream) {
    const float* x     = (const float*)d_in[0];
    const int*   ei    = (const int*)d_in[1];
    const float* ea    = (const float*)d_in[2];
    const float* W1r   = (const float*)d_in[3];
    const float* b1    = (const float*)d_in[4];
    const float* W1t   = (const float*)d_in[5];
    const float* gamma = (const float*)d_in[6];
    const float* beta  = (const float*)d_in[7];
    const float* W2r   = (const float*)d_in[8];
    const float* b2    = (const float*)d_in[9];
    const float* W2t   = (const float*)d_in[10];
    float* out = (float*)d_out;

    char* ws = (char*)d_ws;
    size_t off = 0;
    ushort* featb = (ushort*)(ws + off); off += (size_t)N_NODES * F * 2;        // 12.8 MB (xb)
    ushort* hraw  = (ushort*)(ws + off); off += (size_t)N_NODES * F * 2;        // 12.8 MB (bf16 h)
    u64*    stg   = (u64*)(ws + off);    off += (size_t)P1_BLKS * P1_CHUNK * 8; // 6.4 MB
    uint*   recs  = (uint*)(ws + off);   off += (size_t)NBKT * BKT_STRIDE * 4;  // 8.03 MB
    int*    cntM  = (int*)(ws + off);    off += (size_t)NBKT * NBKT * 4;        // 154 KB
    int*    offM  = (int*)(ws + off);    off += (size_t)NBKT * NBKT * 4;        // 154 KB
    int2*   rng   = (int2*)(ws + off);   off += (size_t)N_NODES * 8;            // 400 KB
    ushort* wb    = (ushort*)(ws + off); off += 4 * 16384 * 2;                  // 128 KB
    float*  Sp    = (float*)(ws + off);  off += NPART * 128 * 4;                // 4 KB
    float*  S2p   = (float*)(ws + off);  off += NPART * 128 * 4;                // 4 KB

    const int* srcp = ei;
    const int* tgtp = ei + N_EDGES;

    // ---- pass 1 (block-local grouping + count/offset matrices) + casts ----
    s1p_k<<<P1_BLKS + CASTX_BLKS + CASTW_BLKS, 256, 0, stream>>>(
        srcp, tgtp, ea, stg, cntM, offM, x, featb, W1r, W1t, W2r, W2t, wb);
    // ---- pass 2: per-bucket independent grouping (also zeroes Sp/S2p) ----
    sort2_k<<<NBKT, 256, 0, stream>>>(cntM, offM, stg, recs, rng, Sp, S2p);

    // ---- layer 1: fused gather+GEMM (+partial BN stats), bf16 h -> hraw ----
    fused_k<1><<<N_RT, 256, 0, stream>>>(featb, rng, recs, wb, wb + 16384, b1,
                                         gamma, beta, Sp, S2p, hraw, out);
    // ---- layer 2: fused BN-finalize + act + gather+GEMM, fp32 out ----
    fused_k<2><<<N_RT, 256, 0, stream>>>(hraw, rng, recs, wb + 32768, wb + 49152, b2,
                                         gamma, beta, Sp, S2p, hraw, out);
}

// Round 7
// 235.643 us; speedup vs baseline: 5.6684x; 5.6684x over previous
//
#include <hip/hip_runtime.h>

#define N_NODES 50000
#define N_EDGES 800000
#define F 128
#define BN_EPS 1e-5f
#define SLOPE 0.22916666666666666f  // RReLU eval slope 11/48

#define NBKT 196          // coarse buckets (tgt>>8)
#define P1_CHUNK 4096
#define P1_EPB 16
#define P1_BLKS 196       // ceil(N_EDGES/P1_CHUNK)
#define CASTX_BLKS 6250   // N_NODES*F/4/256 (exact)
#define CASTW_BLKS 64
#define KSC 18            // ceil(max bucket cnt / 256); Poisson(4082) max ~4400
#define CREC_STRIDE 512   // compact records per tile (max ~435 incl pad-8)
#define N_RT 3125         // N_NODES/16 row-tiles (exact)
#define NPART 8           // BN-stat partial arrays (atomic contention relief)

typedef __attribute__((ext_vector_type(8))) short bf16x8;
typedef __attribute__((ext_vector_type(4))) float f32x4;
typedef unsigned long long u64;

__device__ __forceinline__ float bf2f(ushort u) {
    union { uint i; float f; } v; v.i = (uint)u << 16; return v.f;
}
__device__ __forceinline__ ushort f2bf(float f) {
    union { float f; uint i; } v; v.f = f;
    uint r = v.i + 0x7fffu + ((v.i >> 16) & 1u);  // RNE
    return (ushort)(r >> 16);
}

// ============ s1p: pass 1 (block-local bucket grouping, NO global atomics)
//              + x/W bf16 casts + BN-partial zeroing, one launch ============
// staging record: bits[0:31] = src | bf16(w)<<16 ; bits[32:63] = tgt
__global__ __launch_bounds__(256) void s1p_k(const int* __restrict__ src,
        const int* __restrict__ tgt, const float* __restrict__ ew,
        u64* __restrict__ stg, int* __restrict__ cntM, int* __restrict__ offM,
        const float* __restrict__ x, ushort* __restrict__ xb,
        const float* __restrict__ W1r, const float* __restrict__ W1t,
        const float* __restrict__ W2r, const float* __restrict__ W2t,
        ushort* __restrict__ wb, float* __restrict__ SpZ) {
    const int b = blockIdx.x;
    if (b >= P1_BLKS) {
        if (b < P1_BLKS + CASTX_BLKS) {
            int i = (b - P1_BLKS) * 256 + threadIdx.x;
            float4 v = reinterpret_cast<const float4*>(x)[i];
            ushort4 o;
            o.x = f2bf(v.x); o.y = f2bf(v.y); o.z = f2bf(v.z); o.w = f2bf(v.w);
            reinterpret_cast<ushort4*>(xb)[i] = o;
        } else if (b < P1_BLKS + CASTX_BLKS + CASTW_BLKS) {
            int i = (b - P1_BLKS - CASTX_BLKS) * 256 + threadIdx.x;  // 16384 total
            int m = i >> 12;
            int j = i & 4095;
            const float* sp = (m == 0) ? W1r : (m == 1) ? W1t : (m == 2) ? W2r : W2t;
            float4 v = reinterpret_cast<const float4*>(sp)[j];
            ushort4 o;
            o.x = f2bf(v.x); o.y = f2bf(v.y); o.z = f2bf(v.z); o.w = f2bf(v.w);
            reinterpret_cast<ushort4*>(wb)[i] = o;
        } else {
            // zero BN partials (Sp and S2p are contiguous)
            for (int i = threadIdx.x; i < 2 * NPART * 128; i += 256) SpZ[i] = 0.f;
        }
        return;
    }
    // ---- sort pass 1 (block-local only) ----
    __shared__ uint cnt[256];
    __shared__ uint base[256];
    __shared__ uint lcur[256];
    __shared__ u64 lrec[P1_CHUNK];  // 32 KB

    const int e0 = b * P1_CHUNK;
    const int nE = min(P1_CHUNK, N_EDGES - e0);
    cnt[threadIdx.x] = 0;
    __syncthreads();

    u64 myrec[P1_EPB];
    bool myok[P1_EPB];
#pragma unroll
    for (int k = 0; k < P1_EPB; ++k) {
        int idx = threadIdx.x + (k << 8);
        bool ok = idx < nE;
        myok[k] = ok;
        if (ok) {
            int e = e0 + idx;
            uint t = (uint)tgt[e];
            uint lo = (uint)(ushort)src[e] | ((uint)f2bf(ew[e]) << 16);
            myrec[k] = (u64)lo | ((u64)t << 32);
            atomicAdd(&cnt[t >> 8], 1u);
        }
    }
    __syncthreads();
    uint v = cnt[threadIdx.x];
    base[threadIdx.x] = v;
    __syncthreads();
    for (int o = 1; o < 256; o <<= 1) {
        uint t = (threadIdx.x >= (unsigned)o) ? base[threadIdx.x - o] : 0;
        __syncthreads();
        base[threadIdx.x] += t;
        __syncthreads();
    }
    uint excl = base[threadIdx.x] - v;
    lcur[threadIdx.x] = excl;
    if (threadIdx.x < NBKT) {
        cntM[threadIdx.x * NBKT + b] = (int)v;
        offM[threadIdx.x * NBKT + b] = (int)excl;
    }
    __syncthreads();
#pragma unroll
    for (int k = 0; k < P1_EPB; ++k) {
        if (myok[k]) {
            uint bb = (uint)(myrec[k] >> 40);
            uint slot = atomicAdd(&lcur[bb], 1u);
            lrec[slot] = myrec[k];
        }
    }
    __syncthreads();
    for (int s = threadIdx.x; s < nE; s += 256)
        stg[(size_t)b * P1_CHUNK + s] = lrec[s];
}

// ============ fused extract + gather + dual-GEMM (one block = one 16-row tile) ====
// LAYER 1: in-block extraction replaces sort2 — scan own bucket's staged records,
//   keep this tile's (~256 of ~4082), group per node in LDS (pad-8, zero filler),
//   publish compact recs+rng for layer 2, then round-1 gather (records from LDS)
//   + GEMM(+bias) + bf16 h + partial BN stats.
// LAYER 2: round-1 path verbatim — BN finalize, gather from global compact recs
//   with per-edge BN+RReLU, GEMM(+bias), fp32 out.
template <int LAYER>
__global__ __launch_bounds__(256) void fused_k(
        const ushort* __restrict__ featb, int2* __restrict__ rng,
        uint* __restrict__ crecs, const u64* __restrict__ stg,
        const int* __restrict__ cntM, const int* __restrict__ offM,
        const ushort* __restrict__ Wr, const ushort* __restrict__ Wt,
        const float* __restrict__ bias, const float* __restrict__ gamma,
        const float* __restrict__ beta, float* __restrict__ Sp,
        float* __restrict__ S2p, ushort* __restrict__ outh,
        float* __restrict__ outf) {
    __shared__ __align__(16) uint aggu[16 * 64];   // 16 rows x 128 bf16, XOR-swizzled
    __shared__ __align__(16) float scs[128];
    __shared__ __align__(16) float shs[128];
    __shared__ int sc[256];
    __shared__ int soff[256];
    __shared__ int astart[256];
    __shared__ int lcnt16[16], lcur16[16], p4s[16], nstart[17];
    __shared__ int tot_s;
    __shared__ __align__(16) uint lrec[CREC_STRIDE];  // 2 KB compact tile records

    const int tid = threadIdx.x;
    const int lane = tid & 63;
    const int wave = tid >> 6;
    const int t = blockIdx.x;
    const int row0 = t * 16;

    if (LAYER == 2) {
        // BN finalize: sum NPART partials -> per-feature scale/shift
        if (tid < 128) {
            float s = 0.f, q = 0.f;
#pragma unroll
            for (int p = 0; p < NPART; ++p) {
                s += Sp[p * 128 + tid];
                q += S2p[p * 128 + tid];
            }
            float mean = s * (1.f / N_NODES);
            float var = q * (1.f / N_NODES) - mean * mean;
            float inv = rsqrtf(var + BN_EPS);
            float scv = gamma[tid] * inv;
            scs[tid] = scv;
            shs[tid] = beta[tid] - mean * scv;
        }
        __syncthreads();
    }

    if (LAYER == 1) {
        // ---- extraction: bucket scan -> this tile's records, node-grouped ----
        const int B = t >> 4;
        int c = (tid < NBKT) ? cntM[B * NBKT + tid] : 0;
        soff[tid] = (tid < NBKT) ? offM[B * NBKT + tid] : 0;
        sc[tid] = c;
        if (tid < 16) lcnt16[tid] = 0;
        __syncthreads();
        for (int o = 1; o < 256; o <<= 1) {
            int tv = (tid >= o) ? sc[tid - o] : 0;
            __syncthreads();
            sc[tid] += tv;
            __syncthreads();
        }
        astart[tid] = sc[tid] - c;
        if (tid == 255) tot_s = sc[255];
        __syncthreads();
        const int tot = tot_s;

        u64 myr[KSC];
#pragma unroll
        for (int k = 0; k < KSC; ++k) {
            int i = tid + (k << 8);
            u64 r = ~0ull;   // sentinel: tile id 0x0FFFFFFF never matches
            if (i < tot) {
                int lo = 0;
#pragma unroll
                for (int st = 128; st; st >>= 1) {
                    int cand = lo + st;
                    if (cand < NBKT && astart[cand] <= i) lo = cand;
                }
                int j = i - astart[lo];
                r = stg[(size_t)lo * P1_CHUNK + soff[lo] + j];
                uint tg = (uint)(r >> 32);
                if ((int)(tg >> 4) == t) atomicAdd(&lcnt16[tg & 15u], 1);
            }
            myr[k] = r;
        }
        __syncthreads();
        if (tid == 0) {
            int run = 0;
#pragma unroll
            for (int n = 0; n < 16; ++n) {
                nstart[n] = run;
                int p = (lcnt16[n] + 7) & ~7;   // pad to x8 (zero filler = no-op)
                p4s[n] = p;
                run += p;
            }
            nstart[16] = run;
        }
        __syncthreads();
        const int ptot = nstart[16];
        if (tid < 16) lcur16[tid] = nstart[tid];
        for (int i = tid; i < ptot; i += 256) lrec[i] = 0;
        __syncthreads();
#pragma unroll
        for (int k = 0; k < KSC; ++k) {
            u64 r = myr[k];
            uint tg = (uint)(r >> 32);
            if ((int)(tg >> 4) == t) {
                int p = atomicAdd(&lcur16[tg & 15u], 1);
                lrec[p] = (uint)r;
            }
        }
        __syncthreads();
        // publish for layer 2 (stores overlap the gather below)
        for (int i = tid; i < ptot; i += 256) crecs[t * CREC_STRIDE + i] = lrec[i];
        if (tid < 16)
            rng[row0 + tid] = make_int2(t * CREC_STRIDE + nstart[tid],
                                        t * CREC_STRIDE + nstart[tid] + p4s[tid]);
    }

    // ---- phase 1: each wave gathers 4 nodes into LDS (bf16, swizzled) ----
    const int lane2 = lane * 2;
    float lsc0 = 1.f, lsh0 = 0.f, lsc1 = 1.f, lsh1 = 0.f;
    if (LAYER == 2) {
        lsc0 = scs[lane2]; lsh0 = shs[lane2];
        lsc1 = scs[lane2 + 1]; lsh1 = shs[lane2 + 1];
    }

#pragma unroll
    for (int i = 0; i < 4; ++i) {
        const int r = wave * 4 + i;               // local row 0..15
        float a0 = 0.f, a1 = 0.f;
        int p, pe;
        if (LAYER == 1) { p = nstart[r]; pe = p + p4s[r]; }
        else { int2 rr = rng[row0 + r]; p = rr.x; pe = rr.y; }
        for (; p < pe; p += 8) {
            uint4 ra, rb;
            if (LAYER == 1) {
                ra = *reinterpret_cast<const uint4*>(&lrec[p]);
                rb = *reinterpret_cast<const uint4*>(&lrec[p + 4]);
            } else {
                ra = *reinterpret_cast<const uint4*>(crecs + p);
                rb = *reinterpret_cast<const uint4*>(crecs + p + 4);
            }
            uint u0 = *reinterpret_cast<const uint*>(featb + (size_t)(ra.x & 0xffffu) * F + lane2);
            uint u1 = *reinterpret_cast<const uint*>(featb + (size_t)(ra.y & 0xffffu) * F + lane2);
            uint u2 = *reinterpret_cast<const uint*>(featb + (size_t)(ra.z & 0xffffu) * F + lane2);
            uint u3 = *reinterpret_cast<const uint*>(featb + (size_t)(ra.w & 0xffffu) * F + lane2);
            uint u4 = *reinterpret_cast<const uint*>(featb + (size_t)(rb.x & 0xffffu) * F + lane2);
            uint u5 = *reinterpret_cast<const uint*>(featb + (size_t)(rb.y & 0xffffu) * F + lane2);
            uint u6 = *reinterpret_cast<const uint*>(featb + (size_t)(rb.z & 0xffffu) * F + lane2);
            uint u7 = *reinterpret_cast<const uint*>(featb + (size_t)(rb.w & 0xffffu) * F + lane2);
            float w0 = bf2f((ushort)(ra.x >> 16)), w1 = bf2f((ushort)(ra.y >> 16));
            float w2 = bf2f((ushort)(ra.z >> 16)), w3 = bf2f((ushort)(ra.w >> 16));
            float w4 = bf2f((ushort)(rb.x >> 16)), w5 = bf2f((ushort)(rb.y >> 16));
            float w6 = bf2f((ushort)(rb.z >> 16)), w7 = bf2f((ushort)(rb.w >> 16));
            auto proc = [&](uint u, float w) {
                float t0 = bf2f((ushort)u);
                float t1 = bf2f((ushort)(u >> 16));
                if (LAYER == 2) {
                    t0 = t0 * lsc0 + lsh0; t0 = fmaxf(t0, t0 * SLOPE);
                    t1 = t1 * lsc1 + lsh1; t1 = fmaxf(t1, t1 * SLOPE);
                }
                a0 += w * t0;
                a1 += w * t1;
            };
            proc(u0, w0); proc(u1, w1); proc(u2, w2); proc(u3, w3);
            proc(u4, w4); proc(u5, w5); proc(u6, w6); proc(u7, w7);
        }
        // XOR-swizzled store: byte ^= (row&7)<<4  <=>  uint-idx ^= (row&7)<<2
        aggu[(r * 64 + lane) ^ ((r & 7) << 2)] =
            (uint)f2bf(a0) | ((uint)f2bf(a1) << 16);
    }
    __syncthreads();

    // ---- phase 2: dual GEMM, A(R) from LDS, A(T) from global, W from global ----
    const int quad = lane >> 4;
    const int l16 = lane & 15;
    const int cb = wave * 32;
    const float bias0 = bias[cb + l16];
    const float bias1 = bias[cb + 16 + l16];

    f32x4 acc0 = {0.f, 0.f, 0.f, 0.f};
    f32x4 acc1 = {0.f, 0.f, 0.f, 0.f};

#pragma unroll
    for (int s = 0; s < 4; ++s) {
        const int k0 = s * 32 + quad * 8;
        const int ai = (l16 * 64 + (k0 >> 1)) ^ ((l16 & 7) << 2);
        bf16x8 aR = *reinterpret_cast<const bf16x8*>(&aggu[ai]);
        bf16x8 w0 = *reinterpret_cast<const bf16x8*>(Wr + (cb + l16) * F + k0);
        bf16x8 w1 = *reinterpret_cast<const bf16x8*>(Wr + (cb + 16 + l16) * F + k0);
        acc0 = __builtin_amdgcn_mfma_f32_16x16x32_bf16(aR, w0, acc0, 0, 0, 0);
        acc1 = __builtin_amdgcn_mfma_f32_16x16x32_bf16(aR, w1, acc1, 0, 0, 0);
    }
#pragma unroll
    for (int s = 0; s < 4; ++s) {
        const int k0 = s * 32 + quad * 8;
        bf16x8 aT = *reinterpret_cast<const bf16x8*>(featb + (size_t)(row0 + l16) * F + k0);
        if (LAYER == 2) {
#pragma unroll
            for (int e = 0; e < 8; ++e) {
                float tv = bf2f((ushort)aT[e]) * scs[k0 + e] + shs[k0 + e];
                tv = fmaxf(tv, tv * SLOPE);
                aT[e] = (short)f2bf(tv);
            }
        }
        bf16x8 w0 = *reinterpret_cast<const bf16x8*>(Wt + (cb + l16) * F + k0);
        bf16x8 w1 = *reinterpret_cast<const bf16x8*>(Wt + (cb + 16 + l16) * F + k0);
        acc0 = __builtin_amdgcn_mfma_f32_16x16x32_bf16(aT, w0, acc0, 0, 0, 0);
        acc1 = __builtin_amdgcn_mfma_f32_16x16x32_bf16(aT, w1, acc1, 0, 0, 0);
    }

    // ---- epilogue: C layout col=lane&15, row=quad*4+reg ----
    const int rbase = row0 + quad * 4;
    if (LAYER == 1) {
        float s0 = 0.f, q0 = 0.f, s1 = 0.f, q1 = 0.f;
#pragma unroll
        for (int g = 0; g < 4; ++g) {
            float v0 = acc0[g] + bias0;
            float v1 = acc1[g] + bias1;
            outh[(size_t)(rbase + g) * F + cb + l16] = f2bf(v0);
            outh[(size_t)(rbase + g) * F + cb + 16 + l16] = f2bf(v1);
            s0 += v0; q0 += v0 * v0;
            s1 += v1; q1 += v1 * v1;
        }
        s0 += __shfl_down(s0, 32); s0 += __shfl_down(s0, 16);
        q0 += __shfl_down(q0, 32); q0 += __shfl_down(q0, 16);
        s1 += __shfl_down(s1, 32); s1 += __shfl_down(s1, 16);
        q1 += __shfl_down(q1, 32); q1 += __shfl_down(q1, 16);
        if (lane < 16) {
            float* Sb = Sp + (size_t)(blockIdx.x & (NPART - 1)) * 128;
            float* S2b = S2p + (size_t)(blockIdx.x & (NPART - 1)) * 128;
            unsafeAtomicAdd(&Sb[cb + lane], s0);
            unsafeAtomicAdd(&S2b[cb + lane], q0);
            unsafeAtomicAdd(&Sb[cb + 16 + lane], s1);
            unsafeAtomicAdd(&S2b[cb + 16 + lane], q1);
        }
    } else {
#pragma unroll
        for (int g = 0; g < 4; ++g) {
            outf[(size_t)(rbase + g) * F + cb + l16] = acc0[g] + bias0;
            outf[(size_t)(rbase + g) * F + cb + 16 + l16] = acc1[g] + bias1;
        }
    }
}

extern "C" void kernel_launch(void* const* d_in, const int* in_sizes, int n_in,
                              void* d_out, int out_size, void* d_ws, size_t ws_size,
                              hipStream_t stream) {
    const float* x     = (const float*)d_in[0];
    const int*   ei    = (const int*)d_in[1];
    const float* ea    = (const float*)d_in[2];
    const float* W1r   = (const float*)d_in[3];
    const float* b1    = (const float*)d_in[4];
    const float* W1t   = (const float*)d_in[5];
    const float* gamma = (const float*)d_in[6];
    const float* beta  = (const float*)d_in[7];
    const float* W2r   = (const float*)d_in[8];
    const float* b2    = (const float*)d_in[9];
    const float* W2t   = (const float*)d_in[10];
    float* out = (float*)d_out;

    char* ws = (char*)d_ws;
    size_t off = 0;
    ushort* featb = (ushort*)(ws + off); off += (size_t)N_NODES * F * 2;        // 12.8 MB (xb)
    ushort* hraw  = (ushort*)(ws + off); off += (size_t)N_NODES * F * 2;        // 12.8 MB (bf16 h)
    u64*    stg   = (u64*)(ws + off);    off += (size_t)P1_BLKS * P1_CHUNK * 8; // 6.4 MB
    uint*   crecs = (uint*)(ws + off);   off += (size_t)N_RT * CREC_STRIDE * 4; // 6.4 MB
    int*    cntM  = (int*)(ws + off);    off += (size_t)NBKT * NBKT * 4;        // 154 KB
    int*    offM  = (int*)(ws + off);    off += (size_t)NBKT * NBKT * 4;        // 154 KB
    int2*   rng   = (int2*)(ws + off);   off += (size_t)N_NODES * 8;            // 400 KB
    ushort* wb    = (ushort*)(ws + off); off += 4 * 16384 * 2;                  // 128 KB
    float*  Sp    = (float*)(ws + off);  off += NPART * 128 * 4;                // 4 KB
    float*  S2p   = (float*)(ws + off);  off += NPART * 128 * 4;                // 4 KB (contiguous after Sp)

    const int* srcp = ei;
    const int* tgtp = ei + N_EDGES;

    // ---- pass 1 (bucket grouping + matrices) + casts + BN-partial zeroing ----
    s1p_k<<<P1_BLKS + CASTX_BLKS + CASTW_BLKS + 1, 256, 0, stream>>>(
        srcp, tgtp, ea, stg, cntM, offM, x, featb, W1r, W1t, W2r, W2t, wb, Sp);

    // ---- layer 1: extract (replaces sort2) + gather+GEMM (+BN stats) ----
    fused_k<1><<<N_RT, 256, 0, stream>>>(featb, rng, crecs, stg, cntM, offM,
                                         wb, wb + 16384, b1, gamma, beta,
                                         Sp, S2p, hraw, out);
    // ---- layer 2: BN-finalize + act + gather+GEMM, fp32 out ----
    fused_k<2><<<N_RT, 256, 0, stream>>>(hraw, rng, crecs, stg, cntM, offM,
                                         wb + 32768, wb + 49152, b2, gamma, beta,
                                         Sp, S2p, hraw, out);
}

// Round 8
// 222.423 us; speedup vs baseline: 6.0053x; 1.0594x over previous
//
#include <hip/hip_runtime.h>

#define N_NODES 50000
#define N_EDGES 800000
#define F 128
#define BN_EPS 1e-5f
#define SLOPE 0.22916666666666666f  // RReLU eval slope 11/48

#define NBKT 196          // coarse buckets (tgt>>8)
#define P1_CHUNK 4096
#define P1_EPB 4          // edges/thread at 1024 threads
#define P1_BLKS 196       // ceil(N_EDGES/P1_CHUNK)
#define CASTX_BLKS 1563   // ceil(1600000 float4 / 1024)
#define CASTW_BLKS 16     // 16384 ushort4 / 1024
#define BKT_FINAL_CAP 9984   // cnt_max + pad slack; 39.9 KB LDS
#define BKT_STRIDE 10240     // fixed final-recs stride per bucket
#define MYR_CAP 5            // ceil(max bucket cnt / 1024); max ~4400
#define N_RT 3125         // N_NODES/16 row-tiles (exact)
#define NPART 8           // BN-stat partial arrays (atomic contention relief)

typedef __attribute__((ext_vector_type(8))) short bf16x8;
typedef __attribute__((ext_vector_type(4))) float f32x4;
typedef unsigned long long u64;

__device__ __forceinline__ float bf2f(ushort u) {
    union { uint i; float f; } v; v.i = (uint)u << 16; return v.f;
}
__device__ __forceinline__ ushort f2bf(float f) {
    union { float f; uint i; } v; v.f = f;
    uint r = v.i + 0x7fffu + ((v.i >> 16) & 1u);  // RNE
    return (ushort)(r >> 16);
}

// ============ s1p: pass 1 (block-local bucket grouping) + x/W bf16 casts ============
// 1024 threads/block: 16 waves/CU on the 196 sort blocks (4x latency hiding vs 256).
// staging record: bits[0:31] = src | bf16(w)<<16 ; bits[32:63] = tgt
__global__ __launch_bounds__(1024) void s1p_k(const int* __restrict__ src,
        const int* __restrict__ tgt, const float* __restrict__ ew,
        u64* __restrict__ stg, int* __restrict__ cntM, int* __restrict__ offM,
        const float* __restrict__ x, ushort* __restrict__ xb,
        const float* __restrict__ W1r, const float* __restrict__ W1t,
        const float* __restrict__ W2r, const float* __restrict__ W2t,
        ushort* __restrict__ wb) {
    const int b = blockIdx.x;
    const int tid = threadIdx.x;
    if (b >= P1_BLKS) {
        if (b < P1_BLKS + CASTX_BLKS) {
            int i = (b - P1_BLKS) * 1024 + tid;
            if (i < 1600000) {                       // N_NODES*F/4 float4s
                float4 v = reinterpret_cast<const float4*>(x)[i];
                ushort4 o;
                o.x = f2bf(v.x); o.y = f2bf(v.y); o.z = f2bf(v.z); o.w = f2bf(v.w);
                reinterpret_cast<ushort4*>(xb)[i] = o;
            }
        } else {
            int i = (b - P1_BLKS - CASTX_BLKS) * 1024 + tid;  // 16384 total
            int m = i >> 12;
            int j = i & 4095;
            const float* sp = (m == 0) ? W1r : (m == 1) ? W1t : (m == 2) ? W2r : W2t;
            float4 v = reinterpret_cast<const float4*>(sp)[j];
            ushort4 o;
            o.x = f2bf(v.x); o.y = f2bf(v.y); o.z = f2bf(v.z); o.w = f2bf(v.w);
            reinterpret_cast<ushort4*>(wb)[i] = o;
        }
        return;
    }
    // ---- sort pass 1 (block-local only) ----
    __shared__ uint cnt[256];
    __shared__ uint base[256];
    __shared__ uint lcur[256];
    __shared__ u64 lrec[P1_CHUNK];  // 32 KB

    const int e0 = b * P1_CHUNK;
    const int nE = min(P1_CHUNK, N_EDGES - e0);
    if (tid < 256) cnt[tid] = 0;
    __syncthreads();

    u64 myrec[P1_EPB];
    bool myok[P1_EPB];
#pragma unroll
    for (int k = 0; k < P1_EPB; ++k) {
        int idx = tid + (k << 10);
        bool ok = idx < nE;
        myok[k] = ok;
        if (ok) {
            int e = e0 + idx;
            uint t = (uint)tgt[e];
            uint lo = (uint)(ushort)src[e] | ((uint)f2bf(ew[e]) << 16);
            myrec[k] = (u64)lo | ((u64)t << 32);
            atomicAdd(&cnt[t >> 8], 1u);
        }
    }
    __syncthreads();
    uint v = 0;
    if (tid < 256) { v = cnt[tid]; base[tid] = v; }
    __syncthreads();
    for (int o = 1; o < 256; o <<= 1) {
        uint t = (tid >= o && tid < 256) ? base[tid - o] : 0;
        __syncthreads();
        if (tid < 256) base[tid] += t;
        __syncthreads();
    }
    if (tid < 256) {
        uint excl = base[tid] - v;
        lcur[tid] = excl;
        if (tid < NBKT) {
            cntM[tid * NBKT + b] = (int)v;
            offM[tid * NBKT + b] = (int)excl;
        }
    }
    __syncthreads();
#pragma unroll
    for (int k = 0; k < P1_EPB; ++k) {
        if (myok[k]) {
            uint bb = (uint)(myrec[k] >> 40);
            uint slot = atomicAdd(&lcur[bb], 1u);
            lrec[slot] = myrec[k];
        }
    }
    __syncthreads();
    for (int s = tid; s < nE; s += 1024)
        stg[(size_t)b * P1_CHUNK + s] = lrec[s];
}

// ============ sort pass 2: per bucket, fully independent, 1024 threads ============
__global__ __launch_bounds__(1024) void sort2_k(const int* __restrict__ cntM,
        const int* __restrict__ offM, const u64* __restrict__ stg,
        uint* __restrict__ recs, int2* __restrict__ rng,
        float* __restrict__ Sp, float* __restrict__ S2p) {
    __shared__ int soff[256];
    __shared__ int astart[256];
    __shared__ int lcnt[256];
    __shared__ int lcur[256];
    __shared__ int sc[256];
    __shared__ int tot_s;
    __shared__ uint lrec[BKT_FINAL_CAP];  // 39.9 KB
    const int B = blockIdx.x;
    const int tid = threadIdx.x;

    if (B < NPART && tid < 128) {         // zero BN partials (ready before fused<1>)
        Sp[B * 128 + tid] = 0.f;
        S2p[B * 128 + tid] = 0.f;
    }

    int c = 0;
    if (tid < 256) {
        c = (tid < NBKT) ? cntM[B * NBKT + tid] : 0;
        soff[tid] = (tid < NBKT) ? offM[B * NBKT + tid] : 0;
        sc[tid] = c;
        lcnt[tid] = 0;
    }
    __syncthreads();
    for (int o = 1; o < 256; o <<= 1) {
        int t = (tid >= o && tid < 256) ? sc[tid - o] : 0;
        __syncthreads();
        if (tid < 256) sc[tid] += t;
        __syncthreads();
    }
    if (tid < 256) astart[tid] = sc[tid] - c;
    if (tid == 255) tot_s = sc[255];
    __syncthreads();
    const int tot = tot_s;

    u64 myr[MYR_CAP];
#pragma unroll
    for (int k = 0; k < MYR_CAP; ++k) {
        int i = tid + (k << 10);
        if (i < tot) {
            int lo = 0, hi = NBKT - 1;
            while (lo < hi) {
                int mid = (lo + hi + 1) >> 1;
                if (astart[mid] <= i) lo = mid; else hi = mid - 1;
            }
            int j = i - astart[lo];
            u64 r = stg[(size_t)lo * P1_CHUNK + soff[lo] + j];
            myr[k] = r;
            atomicAdd(&lcnt[(int)(r >> 32) & 255], 1);
        }
    }
    __syncthreads();
    const int node = B * 256 + tid;
    int myp = 0;
    if (tid < 256) {
        int myc = lcnt[tid];
        myp = (myc + 7) & ~7;            // pad to x8 (zero filler = exact no-op)
        if (node >= N_NODES) myp = 0;
        sc[tid] = myp;
    }
    __syncthreads();
    for (int o = 1; o < 256; o <<= 1) {
        int t = (tid >= o && tid < 256) ? sc[tid - o] : 0;
        __syncthreads();
        if (tid < 256) sc[tid] += t;
        __syncthreads();
    }
    const int fbase = B * BKT_STRIDE;
    if (tid < 256) {
        int myoff = sc[tid] - myp;
        lcur[tid] = myoff;
        if (node < N_NODES) rng[node] = make_int2(fbase + myoff, fbase + myoff + myp);
    }
    __syncthreads();
    const int ptot = sc[255];
    for (int i = tid; i < ptot; i += 1024) lrec[i] = 0;
    __syncthreads();
#pragma unroll
    for (int k = 0; k < MYR_CAP; ++k) {
        int i = tid + (k << 10);
        if (i < tot) {
            u64 r = myr[k];
            int n = (int)(r >> 32) & 255;
            int p = atomicAdd(&lcur[n], 1);
            lrec[p] = (uint)r;
        }
    }
    __syncthreads();
    for (int i = tid; i < ptot; i += 1024) recs[fbase + i] = lrec[i];
}

// ============ fused gather + dual-GEMM (one block = one 16-row tile) ============
// R5 structure VERBATIM (proven 60.4-61.6 us).
template <int LAYER>
__global__ __launch_bounds__(256) void fused_k(
        const ushort* __restrict__ featb, const int2* __restrict__ rng,
        const uint* __restrict__ recs, const ushort* __restrict__ Wr,
        const ushort* __restrict__ Wt, const float* __restrict__ bias,
        const float* __restrict__ gamma, const float* __restrict__ beta,
        float* __restrict__ Sp, float* __restrict__ S2p,
        ushort* __restrict__ outh, float* __restrict__ outf) {
    __shared__ __align__(16) uint aggu[16 * 64];   // 16 rows x 128 bf16, XOR-swizzled
    __shared__ __align__(16) float scs[128];
    __shared__ __align__(16) float shs[128];

    const int tid = threadIdx.x;
    const int lane = tid & 63;
    const int wave = tid >> 6;
    const int row0 = blockIdx.x * 16;

    if (LAYER == 2) {
        // BN finalize: sum NPART partials -> per-feature scale/shift
        if (tid < 128) {
            float s = 0.f, q = 0.f;
#pragma unroll
            for (int p = 0; p < NPART; ++p) {
                s += Sp[p * 128 + tid];
                q += S2p[p * 128 + tid];
            }
            float mean = s * (1.f / N_NODES);
            float var = q * (1.f / N_NODES) - mean * mean;
            float inv = rsqrtf(var + BN_EPS);
            float sc = gamma[tid] * inv;
            scs[tid] = sc;
            shs[tid] = beta[tid] - mean * sc;
        }
        __syncthreads();
    }

    // ---- phase 1: each wave gathers 4 nodes into LDS (bf16, swizzled) ----
    const int lane2 = lane * 2;
    float lsc0 = 1.f, lsh0 = 0.f, lsc1 = 1.f, lsh1 = 0.f;
    if (LAYER == 2) {
        lsc0 = scs[lane2]; lsh0 = shs[lane2];
        lsc1 = scs[lane2 + 1]; lsh1 = shs[lane2 + 1];
    }

#pragma unroll
    for (int i = 0; i < 4; ++i) {
        const int r = wave * 4 + i;               // local row 0..15
        const int2 rr = rng[row0 + r];
        float a0 = 0.f, a1 = 0.f;
        for (int p = rr.x; p < rr.y; p += 8) {
            uint4 ra = *reinterpret_cast<const uint4*>(recs + p);
            uint4 rb = *reinterpret_cast<const uint4*>(recs + p + 4);
            uint u0 = *reinterpret_cast<const uint*>(featb + (size_t)(ra.x & 0xffffu) * F + lane2);
            uint u1 = *reinterpret_cast<const uint*>(featb + (size_t)(ra.y & 0xffffu) * F + lane2);
            uint u2 = *reinterpret_cast<const uint*>(featb + (size_t)(ra.z & 0xffffu) * F + lane2);
            uint u3 = *reinterpret_cast<const uint*>(featb + (size_t)(ra.w & 0xffffu) * F + lane2);
            uint u4 = *reinterpret_cast<const uint*>(featb + (size_t)(rb.x & 0xffffu) * F + lane2);
            uint u5 = *reinterpret_cast<const uint*>(featb + (size_t)(rb.y & 0xffffu) * F + lane2);
            uint u6 = *reinterpret_cast<const uint*>(featb + (size_t)(rb.z & 0xffffu) * F + lane2);
            uint u7 = *reinterpret_cast<const uint*>(featb + (size_t)(rb.w & 0xffffu) * F + lane2);
            float w0 = bf2f((ushort)(ra.x >> 16)), w1 = bf2f((ushort)(ra.y >> 16));
            float w2 = bf2f((ushort)(ra.z >> 16)), w3 = bf2f((ushort)(ra.w >> 16));
            float w4 = bf2f((ushort)(rb.x >> 16)), w5 = bf2f((ushort)(rb.y >> 16));
            float w6 = bf2f((ushort)(rb.z >> 16)), w7 = bf2f((ushort)(rb.w >> 16));
            auto proc = [&](uint u, float w) {
                float t0 = bf2f((ushort)u);
                float t1 = bf2f((ushort)(u >> 16));
                if (LAYER == 2) {
                    t0 = t0 * lsc0 + lsh0; t0 = fmaxf(t0, t0 * SLOPE);
                    t1 = t1 * lsc1 + lsh1; t1 = fmaxf(t1, t1 * SLOPE);
                }
                a0 += w * t0;
                a1 += w * t1;
            };
            proc(u0, w0); proc(u1, w1); proc(u2, w2); proc(u3, w3);
            proc(u4, w4); proc(u5, w5); proc(u6, w6); proc(u7, w7);
        }
        // XOR-swizzled store: byte ^= (row&7)<<4  <=>  uint-idx ^= (row&7)<<2
        aggu[(r * 64 + lane) ^ ((r & 7) << 2)] =
            (uint)f2bf(a0) | ((uint)f2bf(a1) << 16);
    }
    __syncthreads();

    // ---- phase 2: dual GEMM, A(R) from LDS, A(T) from global, W from global ----
    const int quad = lane >> 4;
    const int l16 = lane & 15;
    const int cb = wave * 32;
    const float bias0 = bias[cb + l16];
    const float bias1 = bias[cb + 16 + l16];

    f32x4 acc0 = {0.f, 0.f, 0.f, 0.f};
    f32x4 acc1 = {0.f, 0.f, 0.f, 0.f};

#pragma unroll
    for (int s = 0; s < 4; ++s) {
        const int k0 = s * 32 + quad * 8;
        const int ai = (l16 * 64 + (k0 >> 1)) ^ ((l16 & 7) << 2);
        bf16x8 aR = *reinterpret_cast<const bf16x8*>(&aggu[ai]);
        bf16x8 w0 = *reinterpret_cast<const bf16x8*>(Wr + (cb + l16) * F + k0);
        bf16x8 w1 = *reinterpret_cast<const bf16x8*>(Wr + (cb + 16 + l16) * F + k0);
        acc0 = __builtin_amdgcn_mfma_f32_16x16x32_bf16(aR, w0, acc0, 0, 0, 0);
        acc1 = __builtin_amdgcn_mfma_f32_16x16x32_bf16(aR, w1, acc1, 0, 0, 0);
    }
#pragma unroll
    for (int s = 0; s < 4; ++s) {
        const int k0 = s * 32 + quad * 8;
        bf16x8 aT = *reinterpret_cast<const bf16x8*>(featb + (size_t)(row0 + l16) * F + k0);
        if (LAYER == 2) {
#pragma unroll
            for (int e = 0; e < 8; ++e) {
                float t = bf2f((ushort)aT[e]) * scs[k0 + e] + shs[k0 + e];
                t = fmaxf(t, t * SLOPE);
                aT[e] = (short)f2bf(t);
            }
        }
        bf16x8 w0 = *reinterpret_cast<const bf16x8*>(Wt + (cb + l16) * F + k0);
        bf16x8 w1 = *reinterpret_cast<const bf16x8*>(Wt + (cb + 16 + l16) * F + k0);
        acc0 = __builtin_amdgcn_mfma_f32_16x16x32_bf16(aT, w0, acc0, 0, 0, 0);
        acc1 = __builtin_amdgcn_mfma_f32_16x16x32_bf16(aT, w1, acc1, 0, 0, 0);
    }

    // ---- epilogue: C layout col=lane&15, row=quad*4+reg ----
    const int rbase = row0 + quad * 4;
    if (LAYER == 1) {
        float s0 = 0.f, q0 = 0.f, s1 = 0.f, q1 = 0.f;
#pragma unroll
        for (int g = 0; g < 4; ++g) {
            float v0 = acc0[g] + bias0;
            float v1 = acc1[g] + bias1;
            outh[(size_t)(rbase + g) * F + cb + l16] = f2bf(v0);
            outh[(size_t)(rbase + g) * F + cb + 16 + l16] = f2bf(v1);
            s0 += v0; q0 += v0 * v0;
            s1 += v1; q1 += v1 * v1;
        }
        s0 += __shfl_down(s0, 32); s0 += __shfl_down(s0, 16);
        q0 += __shfl_down(q0, 32); q0 += __shfl_down(q0, 16);
        s1 += __shfl_down(s1, 32); s1 += __shfl_down(s1, 16);
        q1 += __shfl_down(q1, 32); q1 += __shfl_down(q1, 16);
        if (lane < 16) {
            float* Sb = Sp + (size_t)(blockIdx.x & (NPART - 1)) * 128;
            float* S2b = S2p + (size_t)(blockIdx.x & (NPART - 1)) * 128;
            unsafeAtomicAdd(&Sb[cb + lane], s0);
            unsafeAtomicAdd(&S2b[cb + lane], q0);
            unsafeAtomicAdd(&Sb[cb + 16 + lane], s1);
            unsafeAtomicAdd(&S2b[cb + 16 + lane], q1);
        }
    } else {
#pragma unroll
        for (int g = 0; g < 4; ++g) {
            outf[(size_t)(rbase + g) * F + cb + l16] = acc0[g] + bias0;
            outf[(size_t)(rbase + g) * F + cb + 16 + l16] = acc1[g] + bias1;
        }
    }
}

extern "C" void kernel_launch(void* const* d_in, const int* in_sizes, int n_in,
                              void* d_out, int out_size, void* d_ws, size_t ws_size,
                              hipStream_t stream) {
    const float* x     = (const float*)d_in[0];
    const int*   ei    = (const int*)d_in[1];
    const float* ea    = (const float*)d_in[2];
    const float* W1r   = (const float*)d_in[3];
    const float* b1    = (const float*)d_in[4];
    const float* W1t   = (const float*)d_in[5];
    const float* gamma = (const float*)d_in[6];
    const float* beta  = (const float*)d_in[7];
    const float* W2r   = (const float*)d_in[8];
    const float* b2    = (const float*)d_in[9];
    const float* W2t   = (const float*)d_in[10];
    float* out = (float*)d_out;

    char* ws = (char*)d_ws;
    size_t off = 0;
    ushort* featb = (ushort*)(ws + off); off += (size_t)N_NODES * F * 2;        // 12.8 MB (xb)
    ushort* hraw  = (ushort*)(ws + off); off += (size_t)N_NODES * F * 2;        // 12.8 MB (bf16 h)
    u64*    stg   = (u64*)(ws + off);    off += (size_t)P1_BLKS * P1_CHUNK * 8; // 6.4 MB
    uint*   recs  = (uint*)(ws + off);   off += (size_t)NBKT * BKT_STRIDE * 4;  // 8.03 MB
    int*    cntM  = (int*)(ws + off);    off += (size_t)NBKT * NBKT * 4;        // 154 KB
    int*    offM  = (int*)(ws + off);    off += (size_t)NBKT * NBKT * 4;        // 154 KB
    int2*   rng   = (int2*)(ws + off);   off += (size_t)N_NODES * 8;            // 400 KB
    ushort* wb    = (ushort*)(ws + off); off += 4 * 16384 * 2;                  // 128 KB
    float*  Sp    = (float*)(ws + off);  off += NPART * 128 * 4;                // 4 KB
    float*  S2p   = (float*)(ws + off);  off += NPART * 128 * 4;                // 4 KB

    const int* srcp = ei;
    const int* tgtp = ei + N_EDGES;

    // ---- pass 1 (block-local grouping + count/offset matrices) + casts, 1024 thr ----
    s1p_k<<<P1_BLKS + CASTX_BLKS + CASTW_BLKS, 1024, 0, stream>>>(
        srcp, tgtp, ea, stg, cntM, offM, x, featb, W1r, W1t, W2r, W2t, wb);
    // ---- pass 2: per-bucket independent grouping, 1024 thr (also zeroes Sp/S2p) ----
    sort2_k<<<NBKT, 1024, 0, stream>>>(cntM, offM, stg, recs, rng, Sp, S2p);

    // ---- layer 1: fused gather+GEMM (+partial BN stats), bf16 h -> hraw ----
    fused_k<1><<<N_RT, 256, 0, stream>>>(featb, rng, recs, wb, wb + 16384, b1,
                                         gamma, beta, Sp, S2p, hraw, out);
    // ---- layer 2: fused BN-finalize + act + gather+GEMM, fp32 out ----
    fused_k<2><<<N_RT, 256, 0, stream>>>(hraw, rng, recs, wb + 32768, wb + 49152, b2,
                                         gamma, beta, Sp, S2p, hraw, out);
}

// Round 9
// 219.070 us; speedup vs baseline: 6.0972x; 1.0153x over previous
//
#include <hip/hip_runtime.h>

#define N_NODES 50000
#define N_EDGES 800000
#define F 128
#define BN_EPS 1e-5f
#define SLOPE 0.22916666666666666f  // RReLU eval slope 11/48

#define NBKT 196          // coarse buckets (tgt>>8)
#define P1_CHUNK 4096
#define P1_EPB 4          // edges/thread at 1024 threads
#define P1_BLKS 196       // ceil(N_EDGES/P1_CHUNK)
#define CASTX_BLKS 1563   // ceil(1600000 float4 / 1024)
#define CASTW_BLKS 16     // 16384 ushort4 / 1024
#define BKT_FINAL_CAP 9984   // cnt_max + pad slack; 39.9 KB LDS
#define BKT_STRIDE 10240     // fixed final-recs stride per bucket
#define MYR_CAP 5            // ceil(max bucket cnt / 1024); max ~4400
#define N_RT 3125         // N_NODES/16 row-tiles (exact)
#define NPART 8           // BN-stat partial arrays (atomic contention relief)

typedef __attribute__((ext_vector_type(8))) short bf16x8;
typedef __attribute__((ext_vector_type(4))) float f32x4;
typedef unsigned long long u64;

__device__ __forceinline__ float bf2f(ushort u) {
    union { uint i; float f; } v; v.i = (uint)u << 16; return v.f;
}
__device__ __forceinline__ ushort f2bf(float f) {
    union { float f; uint i; } v; v.f = f;
    uint r = v.i + 0x7fffu + ((v.i >> 16) & 1u);  // RNE
    return (ushort)(r >> 16);
}

// ============ s1p: pass 1 (block-local bucket grouping) + x/W bf16 casts ============
// 1024 threads/block: 16 waves/CU on the 196 sort blocks (R8, proven).
// staging record: bits[0:31] = src | bf16(w)<<16 ; bits[32:63] = tgt
__global__ __launch_bounds__(1024) void s1p_k(const int* __restrict__ src,
        const int* __restrict__ tgt, const float* __restrict__ ew,
        u64* __restrict__ stg, int* __restrict__ cntM, int* __restrict__ offM,
        const float* __restrict__ x, ushort* __restrict__ xb,
        const float* __restrict__ W1r, const float* __restrict__ W1t,
        const float* __restrict__ W2r, const float* __restrict__ W2t,
        ushort* __restrict__ wb) {
    const int b = blockIdx.x;
    const int tid = threadIdx.x;
    if (b >= P1_BLKS) {
        if (b < P1_BLKS + CASTX_BLKS) {
            int i = (b - P1_BLKS) * 1024 + tid;
            if (i < 1600000) {                       // N_NODES*F/4 float4s
                float4 v = reinterpret_cast<const float4*>(x)[i];
                ushort4 o;
                o.x = f2bf(v.x); o.y = f2bf(v.y); o.z = f2bf(v.z); o.w = f2bf(v.w);
                reinterpret_cast<ushort4*>(xb)[i] = o;
            }
        } else {
            int i = (b - P1_BLKS - CASTX_BLKS) * 1024 + tid;  // 16384 total
            int m = i >> 12;
            int j = i & 4095;
            const float* sp = (m == 0) ? W1r : (m == 1) ? W1t : (m == 2) ? W2r : W2t;
            float4 v = reinterpret_cast<const float4*>(sp)[j];
            ushort4 o;
            o.x = f2bf(v.x); o.y = f2bf(v.y); o.z = f2bf(v.z); o.w = f2bf(v.w);
            reinterpret_cast<ushort4*>(wb)[i] = o;
        }
        return;
    }
    // ---- sort pass 1 (block-local only) ----
    __shared__ uint cnt[256];
    __shared__ uint base[256];
    __shared__ uint lcur[256];
    __shared__ u64 lrec[P1_CHUNK];  // 32 KB

    const int e0 = b * P1_CHUNK;
    const int nE = min(P1_CHUNK, N_EDGES - e0);
    if (tid < 256) cnt[tid] = 0;
    __syncthreads();

    u64 myrec[P1_EPB];
    bool myok[P1_EPB];
#pragma unroll
    for (int k = 0; k < P1_EPB; ++k) {
        int idx = tid + (k << 10);
        bool ok = idx < nE;
        myok[k] = ok;
        if (ok) {
            int e = e0 + idx;
            uint t = (uint)tgt[e];
            uint lo = (uint)(ushort)src[e] | ((uint)f2bf(ew[e]) << 16);
            myrec[k] = (u64)lo | ((u64)t << 32);
            atomicAdd(&cnt[t >> 8], 1u);
        }
    }
    __syncthreads();
    uint v = 0;
    if (tid < 256) { v = cnt[tid]; base[tid] = v; }
    __syncthreads();
    for (int o = 1; o < 256; o <<= 1) {
        uint t = (tid >= o && tid < 256) ? base[tid - o] : 0;
        __syncthreads();
        if (tid < 256) base[tid] += t;
        __syncthreads();
    }
    if (tid < 256) {
        uint excl = base[tid] - v;
        lcur[tid] = excl;
        if (tid < NBKT) {
            cntM[tid * NBKT + b] = (int)v;
            offM[tid * NBKT + b] = (int)excl;
        }
    }
    __syncthreads();
#pragma unroll
    for (int k = 0; k < P1_EPB; ++k) {
        if (myok[k]) {
            uint bb = (uint)(myrec[k] >> 40);
            uint slot = atomicAdd(&lcur[bb], 1u);
            lrec[slot] = myrec[k];
        }
    }
    __syncthreads();
    for (int s = tid; s < nE; s += 1024)
        stg[(size_t)b * P1_CHUNK + s] = lrec[s];
}

// ============ sort pass 2: per bucket, fully independent, 1024 threads (R8) ========
__global__ __launch_bounds__(1024) void sort2_k(const int* __restrict__ cntM,
        const int* __restrict__ offM, const u64* __restrict__ stg,
        uint* __restrict__ recs, int2* __restrict__ rng,
        float* __restrict__ Sp, float* __restrict__ S2p) {
    __shared__ int soff[256];
    __shared__ int astart[256];
    __shared__ int lcnt[256];
    __shared__ int lcur[256];
    __shared__ int sc[256];
    __shared__ int tot_s;
    __shared__ uint lrec[BKT_FINAL_CAP];  // 39.9 KB
    const int B = blockIdx.x;
    const int tid = threadIdx.x;

    if (B < NPART && tid < 128) {         // zero BN partials (ready before fused<1>)
        Sp[B * 128 + tid] = 0.f;
        S2p[B * 128 + tid] = 0.f;
    }

    int c = 0;
    if (tid < 256) {
        c = (tid < NBKT) ? cntM[B * NBKT + tid] : 0;
        soff[tid] = (tid < NBKT) ? offM[B * NBKT + tid] : 0;
        sc[tid] = c;
        lcnt[tid] = 0;
    }
    __syncthreads();
    for (int o = 1; o < 256; o <<= 1) {
        int t = (tid >= o && tid < 256) ? sc[tid - o] : 0;
        __syncthreads();
        if (tid < 256) sc[tid] += t;
        __syncthreads();
    }
    if (tid < 256) astart[tid] = sc[tid] - c;
    if (tid == 255) tot_s = sc[255];
    __syncthreads();
    const int tot = tot_s;

    u64 myr[MYR_CAP];
#pragma unroll
    for (int k = 0; k < MYR_CAP; ++k) {
        int i = tid + (k << 10);
        if (i < tot) {
            int lo = 0, hi = NBKT - 1;
            while (lo < hi) {
                int mid = (lo + hi + 1) >> 1;
                if (astart[mid] <= i) lo = mid; else hi = mid - 1;
            }
            int j = i - astart[lo];
            u64 r = stg[(size_t)lo * P1_CHUNK + soff[lo] + j];
            myr[k] = r;
            atomicAdd(&lcnt[(int)(r >> 32) & 255], 1);
        }
    }
    __syncthreads();
    const int node = B * 256 + tid;
    int myp = 0;
    if (tid < 256) {
        int myc = lcnt[tid];
        myp = (myc + 7) & ~7;            // pad to x8 (zero filler = exact no-op)
        if (node >= N_NODES) myp = 0;
        sc[tid] = myp;
    }
    __syncthreads();
    for (int o = 1; o < 256; o <<= 1) {
        int t = (tid >= o && tid < 256) ? sc[tid - o] : 0;
        __syncthreads();
        if (tid < 256) sc[tid] += t;
        __syncthreads();
    }
    const int fbase = B * BKT_STRIDE;
    if (tid < 256) {
        int myoff = sc[tid] - myp;
        lcur[tid] = myoff;
        if (node < N_NODES) rng[node] = make_int2(fbase + myoff, fbase + myoff + myp);
    }
    __syncthreads();
    const int ptot = sc[255];
    for (int i = tid; i < ptot; i += 1024) lrec[i] = 0;
    __syncthreads();
#pragma unroll
    for (int k = 0; k < MYR_CAP; ++k) {
        int i = tid + (k << 10);
        if (i < tot) {
            u64 r = myr[k];
            int n = (int)(r >> 32) & 255;
            int p = atomicAdd(&lcur[n], 1);
            lrec[p] = (uint)r;
        }
    }
    __syncthreads();
    for (int i = tid; i < ptot; i += 1024) recs[fbase + i] = lrec[i];
}

// ============ fused gather + dual-GEMM (one block = one 16-row tile) ============
// Gather v2: the wave's 4 consecutive nodes form ONE contiguous padded record
// range (sort2 lays node ranges back-to-back; tiles never span buckets). Stream
// it in a single loop with the next 8-record group prefetched one iteration
// ahead (rec latency hidden under feature loads + FMAs). Group sums steered to
// 1-of-4 static accumulator pairs by a wave-uniform boundary compare (pad-8
// guarantees groups never straddle nodes).
template <int LAYER>
__global__ __launch_bounds__(256) void fused_k(
        const ushort* __restrict__ featb, const int2* __restrict__ rng,
        const uint* __restrict__ recs, const ushort* __restrict__ Wr,
        const ushort* __restrict__ Wt, const float* __restrict__ bias,
        const float* __restrict__ gamma, const float* __restrict__ beta,
        float* __restrict__ Sp, float* __restrict__ S2p,
        ushort* __restrict__ outh, float* __restrict__ outf) {
    __shared__ __align__(16) uint aggu[16 * 64];   // 16 rows x 128 bf16, XOR-swizzled
    __shared__ __align__(16) float scs[128];
    __shared__ __align__(16) float shs[128];

    const int tid = threadIdx.x;
    const int lane = tid & 63;
    const int wave = tid >> 6;
    const int row0 = blockIdx.x * 16;

    if (LAYER == 2) {
        // BN finalize: sum NPART partials -> per-feature scale/shift
        if (tid < 128) {
            float s = 0.f, q = 0.f;
#pragma unroll
            for (int p = 0; p < NPART; ++p) {
                s += Sp[p * 128 + tid];
                q += S2p[p * 128 + tid];
            }
            float mean = s * (1.f / N_NODES);
            float var = q * (1.f / N_NODES) - mean * mean;
            float inv = rsqrtf(var + BN_EPS);
            float sc = gamma[tid] * inv;
            scs[tid] = sc;
            shs[tid] = beta[tid] - mean * sc;
        }
        __syncthreads();
    }

    // ---- phase 1: pipelined streamed gather over the wave's 4-node range ----
    const int lane2 = lane * 2;
    float lsc0 = 1.f, lsh0 = 0.f, lsc1 = 1.f, lsh1 = 0.f;
    if (LAYER == 2) {
        lsc0 = scs[lane2]; lsh0 = shs[lane2];
        lsc1 = scs[lane2 + 1]; lsh1 = shs[lane2 + 1];
    }

    const int nb = row0 + wave * 4;
    // rng[nb..nb+3] via two 16B loads (nb is even)
    int4 RA = reinterpret_cast<const int4*>(rng)[nb >> 1];       // rng[nb], rng[nb+1]
    int4 RB = reinterpret_cast<const int4*>(rng)[(nb >> 1) + 1]; // rng[nb+2], rng[nb+3]
    int p = RA.x;                  // start of node 0
    const int b1 = RA.z;           // start of node 1
    const int b2 = RB.x;           // start of node 2
    const int b3 = RB.z;           // start of node 3
    const int pend = RB.w;         // end of node 3

    float a00 = 0.f, a01 = 0.f, a10 = 0.f, a11 = 0.f;
    float a20 = 0.f, a21 = 0.f, a30 = 0.f, a31 = 0.f;

    if (p < pend) {
        uint4 ra = *reinterpret_cast<const uint4*>(recs + p);
        uint4 rb = *reinterpret_cast<const uint4*>(recs + p + 4);
        while (p < pend) {
            const int pn = p + 8;
            const int pf = (pn < pend) ? pn : p;   // safe prefetch addr (uniform)
            uint4 na = *reinterpret_cast<const uint4*>(recs + pf);
            uint4 nb_ = *reinterpret_cast<const uint4*>(recs + pf + 4);
            uint u0 = *reinterpret_cast<const uint*>(featb + (size_t)(ra.x & 0xffffu) * F + lane2);
            uint u1 = *reinterpret_cast<const uint*>(featb + (size_t)(ra.y & 0xffffu) * F + lane2);
            uint u2 = *reinterpret_cast<const uint*>(featb + (size_t)(ra.z & 0xffffu) * F + lane2);
            uint u3 = *reinterpret_cast<const uint*>(featb + (size_t)(ra.w & 0xffffu) * F + lane2);
            uint u4 = *reinterpret_cast<const uint*>(featb + (size_t)(rb.x & 0xffffu) * F + lane2);
            uint u5 = *reinterpret_cast<const uint*>(featb + (size_t)(rb.y & 0xffffu) * F + lane2);
            uint u6 = *reinterpret_cast<const uint*>(featb + (size_t)(rb.z & 0xffffu) * F + lane2);
            uint u7 = *reinterpret_cast<const uint*>(featb + (size_t)(rb.w & 0xffffu) * F + lane2);
            float w0 = bf2f((ushort)(ra.x >> 16)), w1 = bf2f((ushort)(ra.y >> 16));
            float w2 = bf2f((ushort)(ra.z >> 16)), w3 = bf2f((ushort)(ra.w >> 16));
            float w4 = bf2f((ushort)(rb.x >> 16)), w5 = bf2f((ushort)(rb.y >> 16));
            float w6 = bf2f((ushort)(rb.z >> 16)), w7 = bf2f((ushort)(rb.w >> 16));
            float g0 = 0.f, g1 = 0.f;
            auto proc = [&](uint u, float w) {
                float t0 = bf2f((ushort)u);
                float t1 = bf2f((ushort)(u >> 16));
                if (LAYER == 2) {
                    t0 = t0 * lsc0 + lsh0; t0 = fmaxf(t0, t0 * SLOPE);
                    t1 = t1 * lsc1 + lsh1; t1 = fmaxf(t1, t1 * SLOPE);
                }
                g0 += w * t0;
                g1 += w * t1;
            };
            proc(u0, w0); proc(u1, w1); proc(u2, w2); proc(u3, w3);
            proc(u4, w4); proc(u5, w5); proc(u6, w6); proc(u7, w7);
            // steer group sum to its node's accumulator (wave-uniform branch)
            if (p >= b3)      { a30 += g0; a31 += g1; }
            else if (p >= b2) { a20 += g0; a21 += g1; }
            else if (p >= b1) { a10 += g0; a11 += g1; }
            else              { a00 += g0; a01 += g1; }
            ra = na; rb = nb_;
            p = pn;
        }
    }

    // XOR-swizzled stores: byte ^= (row&7)<<4  <=>  uint-idx ^= (row&7)<<2
    {
        const int r0l = wave * 4;
        aggu[((r0l + 0) * 64 + lane) ^ (((r0l + 0) & 7) << 2)] =
            (uint)f2bf(a00) | ((uint)f2bf(a01) << 16);
        aggu[((r0l + 1) * 64 + lane) ^ (((r0l + 1) & 7) << 2)] =
            (uint)f2bf(a10) | ((uint)f2bf(a11) << 16);
        aggu[((r0l + 2) * 64 + lane) ^ (((r0l + 2) & 7) << 2)] =
            (uint)f2bf(a20) | ((uint)f2bf(a21) << 16);
        aggu[((r0l + 3) * 64 + lane) ^ (((r0l + 3) & 7) << 2)] =
            (uint)f2bf(a30) | ((uint)f2bf(a31) << 16);
    }
    __syncthreads();

    // ---- phase 2: dual GEMM, A(R) from LDS, A(T) from global, W from global ----
    const int quad = lane >> 4;
    const int l16 = lane & 15;
    const int cb = wave * 32;
    const float bias0 = bias[cb + l16];
    const float bias1 = bias[cb + 16 + l16];

    f32x4 acc0 = {0.f, 0.f, 0.f, 0.f};
    f32x4 acc1 = {0.f, 0.f, 0.f, 0.f};

#pragma unroll
    for (int s = 0; s < 4; ++s) {
        const int k0 = s * 32 + quad * 8;
        const int ai = (l16 * 64 + (k0 >> 1)) ^ ((l16 & 7) << 2);
        bf16x8 aR = *reinterpret_cast<const bf16x8*>(&aggu[ai]);
        bf16x8 w0 = *reinterpret_cast<const bf16x8*>(Wr + (cb + l16) * F + k0);
        bf16x8 w1 = *reinterpret_cast<const bf16x8*>(Wr + (cb + 16 + l16) * F + k0);
        acc0 = __builtin_amdgcn_mfma_f32_16x16x32_bf16(aR, w0, acc0, 0, 0, 0);
        acc1 = __builtin_amdgcn_mfma_f32_16x16x32_bf16(aR, w1, acc1, 0, 0, 0);
    }
#pragma unroll
    for (int s = 0; s < 4; ++s) {
        const int k0 = s * 32 + quad * 8;
        bf16x8 aT = *reinterpret_cast<const bf16x8*>(featb + (size_t)(row0 + l16) * F + k0);
        if (LAYER == 2) {
#pragma unroll
            for (int e = 0; e < 8; ++e) {
                float t = bf2f((ushort)aT[e]) * scs[k0 + e] + shs[k0 + e];
                t = fmaxf(t, t * SLOPE);
                aT[e] = (short)f2bf(t);
            }
        }
        bf16x8 w0 = *reinterpret_cast<const bf16x8*>(Wt + (cb + l16) * F + k0);
        bf16x8 w1 = *reinterpret_cast<const bf16x8*>(Wt + (cb + 16 + l16) * F + k0);
        acc0 = __builtin_amdgcn_mfma_f32_16x16x32_bf16(aT, w0, acc0, 0, 0, 0);
        acc1 = __builtin_amdgcn_mfma_f32_16x16x32_bf16(aT, w1, acc1, 0, 0, 0);
    }

    // ---- epilogue: C layout col=lane&15, row=quad*4+reg ----
    const int rbase = row0 + quad * 4;
    if (LAYER == 1) {
        float s0 = 0.f, q0 = 0.f, s1 = 0.f, q1 = 0.f;
#pragma unroll
        for (int g = 0; g < 4; ++g) {
            float v0 = acc0[g] + bias0;
            float v1 = acc1[g] + bias1;
            outh[(size_t)(rbase + g) * F + cb + l16] = f2bf(v0);
            outh[(size_t)(rbase + g) * F + cb + 16 + l16] = f2bf(v1);
            s0 += v0; q0 += v0 * v0;
            s1 += v1; q1 += v1 * v1;
        }
        s0 += __shfl_down(s0, 32); s0 += __shfl_down(s0, 16);
        q0 += __shfl_down(q0, 32); q0 += __shfl_down(q0, 16);
        s1 += __shfl_down(s1, 32); s1 += __shfl_down(s1, 16);
        q1 += __shfl_down(q1, 32); q1 += __shfl_down(q1, 16);
        if (lane < 16) {
            float* Sb = Sp + (size_t)(blockIdx.x & (NPART - 1)) * 128;
            float* S2b = S2p + (size_t)(blockIdx.x & (NPART - 1)) * 128;
            unsafeAtomicAdd(&Sb[cb + lane], s0);
            unsafeAtomicAdd(&S2b[cb + lane], q0);
            unsafeAtomicAdd(&Sb[cb + 16 + lane], s1);
            unsafeAtomicAdd(&S2b[cb + 16 + lane], q1);
        }
    } else {
#pragma unroll
        for (int g = 0; g < 4; ++g) {
            outf[(size_t)(rbase + g) * F + cb + l16] = acc0[g] + bias0;
            outf[(size_t)(rbase + g) * F + cb + 16 + l16] = acc1[g] + bias1;
        }
    }
}

extern "C" void kernel_launch(void* const* d_in, const int* in_sizes, int n_in,
                              void* d_out, int out_size, void* d_ws, size_t ws_size,
                              hipStream_t stream) {
    const float* x     = (const float*)d_in[0];
    const int*   ei    = (const int*)d_in[1];
    const float* ea    = (const float*)d_in[2];
    const float* W1r   = (const float*)d_in[3];
    const float* b1    = (const float*)d_in[4];
    const float* W1t   = (const float*)d_in[5];
    const float* gamma = (const float*)d_in[6];
    const float* beta  = (const float*)d_in[7];
    const float* W2r   = (const float*)d_in[8];
    const float* b2    = (const float*)d_in[9];
    const float* W2t   = (const float*)d_in[10];
    float* out = (float*)d_out;

    char* ws = (char*)d_ws;
    size_t off = 0;
    ushort* featb = (ushort*)(ws + off); off += (size_t)N_NODES * F * 2;        // 12.8 MB (xb)
    ushort* hraw  = (ushort*)(ws + off); off += (size_t)N_NODES * F * 2;        // 12.8 MB (bf16 h)
    u64*    stg   = (u64*)(ws + off);    off += (size_t)P1_BLKS * P1_CHUNK * 8; // 6.4 MB
    uint*   recs  = (uint*)(ws + off);   off += (size_t)NBKT * BKT_STRIDE * 4;  // 8.03 MB
    int*    cntM  = (int*)(ws + off);    off += (size_t)NBKT * NBKT * 4;        // 154 KB
    int*    offM  = (int*)(ws + off);    off += (size_t)NBKT * NBKT * 4;        // 154 KB
    int2*   rng   = (int2*)(ws + off);   off += (size_t)N_NODES * 8;            // 400 KB
    ushort* wb    = (ushort*)(ws + off); off += 4 * 16384 * 2;                  // 128 KB
    float*  Sp    = (float*)(ws + off);  off += NPART * 128 * 4;                // 4 KB
    float*  S2p   = (float*)(ws + off);  off += NPART * 128 * 4;                // 4 KB

    const int* srcp = ei;
    const int* tgtp = ei + N_EDGES;

    // ---- pass 1 (block-local grouping + count/offset matrices) + casts, 1024 thr ----
    s1p_k<<<P1_BLKS + CASTX_BLKS + CASTW_BLKS, 1024, 0, stream>>>(
        srcp, tgtp, ea, stg, cntM, offM, x, featb, W1r, W1t, W2r, W2t, wb);
    // ---- pass 2: per-bucket independent grouping, 1024 thr (also zeroes Sp/S2p) ----
    sort2_k<<<NBKT, 1024, 0, stream>>>(cntM, offM, stg, recs, rng, Sp, S2p);

    // ---- layer 1: fused gather+GEMM (+partial BN stats), bf16 h -> hraw ----
    fused_k<1><<<N_RT, 256, 0, stream>>>(featb, rng, recs, wb, wb + 16384, b1,
                                         gamma, beta, Sp, S2p, hraw, out);
    // ---- layer 2: fused BN-finalize + act + gather+GEMM, fp32 out ----
    fused_k<2><<<N_RT, 256, 0, stream>>>(hraw, rng, recs, wb + 32768, wb + 49152, b2,
                                         gamma, beta, Sp, S2p, hraw, out);
}